// Round 3
// baseline (10352.898 us; speedup 1.0000x reference)
//
#include <hip/hip_runtime.h>
#include <hip/hip_bf16.h>
#include <hip/hip_cooperative_groups.h>

namespace cg = cooperative_groups;

#define TT 96
#define BB 32
#define DIN 256
#define HH 512
#define VV 128

// ---------------- Phase A: Z[t][g][h][b] = sum_d x[b][t][d] * Wg[t][h][d] ----------------
// grid: 96 t * 16 tiles (gate, 128-row block), 256 threads.
// W staged in LDS in 32-k chunks (reg-pipelined), XOR-swizzled; x staged once.
__global__ __launch_bounds__(256) void phaseA_kernel(
    const float* __restrict__ x,
    const float* __restrict__ Wf, const float* __restrict__ Wi,
    const float* __restrict__ Wc, const float* __restrict__ Wo,
    float* __restrict__ Z)
{
    int bid  = blockIdx.x;
    int t    = bid >> 4;
    int tile = bid & 15;
    int g    = tile >> 2;
    int h0   = (tile & 3) * 128;
    const float* W = (g == 0) ? Wf : (g == 1) ? Wi : (g == 2) ? Wc : Wo;

    __shared__ float4 Xs4[32 * 64];   // 32 KB; (b, q) at [b*64 + (q ^ (b&15))]
    __shared__ float4 Wc4[128 * 8];   // 16 KB; slot s=row*8+qs holds global quad qs ^ ((row>>2)&7)

    int tid = threadIdx.x;
    // stage x[b][t][0..255]
    {
        int b   = tid >> 3;
        int kq8 = tid & 7;
        const float* src = x + ((size_t)b * TT + t) * DIN;
        int bx = b & 15;
        #pragma unroll
        for (int j = 0; j < 8; ++j) {
            int q = kq8 * 8 + j;
            Xs4[b * 64 + (q ^ bx)] = *reinterpret_cast<const float4*>(src + q * 4);
        }
    }

    int rg = tid >> 3;          // 32 row-groups of 4 rows
    int bg = tid & 7;           // b = c*8 + bg
    const float* wbase = W + ((size_t)t * HH + h0) * DIN;

    // per-thread staging slots: s = j*256 + tid
    int srow[4], sgq[4];
    #pragma unroll
    for (int j = 0; j < 4; ++j) {
        int s = j * 256 + tid;
        srow[j] = s >> 3;
        sgq[j]  = (s & 7) ^ ((srow[j] >> 2) & 7);
    }

    float4 stg[4];
    #pragma unroll
    for (int j = 0; j < 4; ++j)
        stg[j] = *reinterpret_cast<const float4*>(wbase + (size_t)srow[j] * DIN + sgq[j] * 4);

    float acc[4][4];
    #pragma unroll
    for (int r = 0; r < 4; ++r)
        #pragma unroll
        for (int c = 0; c < 4; ++c) acc[r][c] = 0.f;

    for (int kc = 0; kc < 8; ++kc) {
        __syncthreads();                       // Wc4 free (covers X stage on first iter)
        #pragma unroll
        for (int j = 0; j < 4; ++j) Wc4[j * 256 + tid] = stg[j];
        __syncthreads();
        if (kc < 7) {
            #pragma unroll
            for (int j = 0; j < 4; ++j)
                stg[j] = *reinterpret_cast<const float4*>(
                    wbase + (size_t)srow[j] * DIN + (kc + 1) * 32 + sgq[j] * 4);
        }
        #pragma unroll
        for (int q = 0; q < 8; ++q) {
            float4 xv[4], wv[4];
            #pragma unroll
            for (int c = 0; c < 4; ++c) {
                int b = c * 8 + bg;
                xv[c] = Xs4[b * 64 + ((kc * 8 + q) ^ (b & 15))];
            }
            #pragma unroll
            for (int r = 0; r < 4; ++r)
                wv[r] = Wc4[(rg * 4 + r) * 8 + (q ^ (rg & 7))];
            #pragma unroll
            for (int r = 0; r < 4; ++r)
                #pragma unroll
                for (int c = 0; c < 4; ++c) {
                    acc[r][c] = fmaf(wv[r].x, xv[c].x, acc[r][c]);
                    acc[r][c] = fmaf(wv[r].y, xv[c].y, acc[r][c]);
                    acc[r][c] = fmaf(wv[r].z, xv[c].z, acc[r][c]);
                    acc[r][c] = fmaf(wv[r].w, xv[c].w, acc[r][c]);
                }
        }
    }

    size_t zbase = ((size_t)(t * 4 + g) * HH + h0 + rg * 4) * BB;
    #pragma unroll
    for (int r = 0; r < 4; ++r)
        #pragma unroll
        for (int c = 0; c < 4; ++c)
            Z[zbase + (size_t)r * BB + c * 8 + bg] = acc[r][c];
}

// ---------------- Phase B: persistent cooperative kernel, all 96 steps ----------------
// 512 blocks (1 h-row each) x 256 threads (16 k-splits * 16 b-pairs), 2 blocks/CU.
// c stays in registers; W[t+1] prefetched into L2 before each grid sync.
__global__ __launch_bounds__(256, 2) void lstm_persistent(
    const float* __restrict__ Whf, const float* __restrict__ Whi,
    const float* __restrict__ Whc, const float* __restrict__ Who,
    const float* __restrict__ bf,  const float* __restrict__ bi,
    const float* __restrict__ bc,  const float* __restrict__ bo,
    const float* __restrict__ Z,   float* __restrict__ Hall)
{
    cg::grid_group grid = cg::this_grid();

    int h   = blockIdx.x;
    int tid = threadIdx.x;
    int ks  = tid >> 4;          // 0..15, k-chunk of 32
    int bg  = tid & 15;          // b = 2bg, 2bg+1

    __shared__ float pre[16][4][32];
    __shared__ float act[4][32];

    float creg = 0.f;            // cell state for b = tid (tid < 32)

    for (int t = 0; t < TT; ++t) {
        float a[4][2];
        #pragma unroll
        for (int gg = 0; gg < 4; ++gg) { a[gg][0] = 0.f; a[gg][1] = 0.f; }

        if (t > 0) {
            int k0 = ks * 32;
            const float* hp = Hall + (size_t)(t - 1) * HH * BB + (size_t)k0 * BB + 2 * bg;
            size_t wo = ((size_t)t * HH + h) * HH + k0;
            const float* wF = Whf + wo;
            const float* wI = Whi + wo;
            const float* wC = Whc + wo;
            const float* wO = Who + wo;
            #pragma unroll
            for (int q = 0; q < 8; ++q) {
                float2 h0v = *reinterpret_cast<const float2*>(hp + (size_t)(q * 4 + 0) * BB);
                float2 h1v = *reinterpret_cast<const float2*>(hp + (size_t)(q * 4 + 1) * BB);
                float2 h2v = *reinterpret_cast<const float2*>(hp + (size_t)(q * 4 + 2) * BB);
                float2 h3v = *reinterpret_cast<const float2*>(hp + (size_t)(q * 4 + 3) * BB);
                float4 w;
                w = *reinterpret_cast<const float4*>(wF + q * 4);
                a[0][0] = fmaf(w.x, h0v.x, a[0][0]); a[0][1] = fmaf(w.x, h0v.y, a[0][1]);
                a[0][0] = fmaf(w.y, h1v.x, a[0][0]); a[0][1] = fmaf(w.y, h1v.y, a[0][1]);
                a[0][0] = fmaf(w.z, h2v.x, a[0][0]); a[0][1] = fmaf(w.z, h2v.y, a[0][1]);
                a[0][0] = fmaf(w.w, h3v.x, a[0][0]); a[0][1] = fmaf(w.w, h3v.y, a[0][1]);
                w = *reinterpret_cast<const float4*>(wI + q * 4);
                a[1][0] = fmaf(w.x, h0v.x, a[1][0]); a[1][1] = fmaf(w.x, h0v.y, a[1][1]);
                a[1][0] = fmaf(w.y, h1v.x, a[1][0]); a[1][1] = fmaf(w.y, h1v.y, a[1][1]);
                a[1][0] = fmaf(w.z, h2v.x, a[1][0]); a[1][1] = fmaf(w.z, h2v.y, a[1][1]);
                a[1][0] = fmaf(w.w, h3v.x, a[1][0]); a[1][1] = fmaf(w.w, h3v.y, a[1][1]);
                w = *reinterpret_cast<const float4*>(wC + q * 4);
                a[2][0] = fmaf(w.x, h0v.x, a[2][0]); a[2][1] = fmaf(w.x, h0v.y, a[2][1]);
                a[2][0] = fmaf(w.y, h1v.x, a[2][0]); a[2][1] = fmaf(w.y, h1v.y, a[2][1]);
                a[2][0] = fmaf(w.z, h2v.x, a[2][0]); a[2][1] = fmaf(w.z, h2v.y, a[2][1]);
                a[2][0] = fmaf(w.w, h3v.x, a[2][0]); a[2][1] = fmaf(w.w, h3v.y, a[2][1]);
                w = *reinterpret_cast<const float4*>(wO + q * 4);
                a[3][0] = fmaf(w.x, h0v.x, a[3][0]); a[3][1] = fmaf(w.x, h0v.y, a[3][1]);
                a[3][0] = fmaf(w.y, h1v.x, a[3][0]); a[3][1] = fmaf(w.y, h1v.y, a[3][1]);
                a[3][0] = fmaf(w.z, h2v.x, a[3][0]); a[3][1] = fmaf(w.z, h2v.y, a[3][1]);
                a[3][0] = fmaf(w.w, h3v.x, a[3][0]); a[3][1] = fmaf(w.w, h3v.y, a[3][1]);
            }
        }
        #pragma unroll
        for (int gg = 0; gg < 4; ++gg) {
            pre[ks][gg][2 * bg]     = a[gg][0];
            pre[ks][gg][2 * bg + 1] = a[gg][1];
        }
        __syncthreads();

        if (tid < 128) {
            int gg = tid >> 5;
            int b  = tid & 31;
            float s = 0.f;
            #pragma unroll
            for (int k2 = 0; k2 < 16; ++k2) s += pre[k2][gg][b];
            s += Z[((size_t)(t * 4 + gg) * HH + h) * BB + b];
            if (t > 0) {
                const float* bp = (gg == 0) ? bf : (gg == 1) ? bi : (gg == 2) ? bc : bo;
                s += bp[t * HH + h];
            }
            act[gg][b] = (gg == 2) ? tanhf(s) : 1.f / (1.f + __expf(-s));
        }
        __syncthreads();

        if (tid < 32) {
            int b = tid;
            float cn = act[0][b] * creg + act[1][b] * act[2][b];
            creg = cn;
            Hall[((size_t)t * HH + h) * BB + b] = act[3][b] * tanhf(cn);
        }

        // prefetch W[t+1] (and Z[t+1]) for this h-row into this XCD's L2
        if (t + 1 < TT) {
            size_t wo = ((size_t)(t + 1) * HH + h) * HH;
            float s = 0.f;
            #pragma unroll
            for (int j = 0; j < 2; ++j) {
                int flat = j * 256 + tid;        // 0..511 float4s across 4 gates
                int gg = flat >> 7;
                int q  = flat & 127;
                const float* wp = ((gg == 0) ? Whf : (gg == 1) ? Whi : (gg == 2) ? Whc : Who)
                                  + wo + q * 4;
                float4 v = *reinterpret_cast<const float4*>(wp);
                s += v.x + v.y + v.z + v.w;
            }
            if (tid < 128)
                s += Z[((size_t)((t + 1) * 4 + (tid >> 5)) * HH + h) * BB + (tid & 31)];
            asm volatile("" :: "v"(s));
        }

        __threadfence();
        grid.sync();
    }
}

// ---------------- Phase C ----------------
__global__ __launch_bounds__(256) void phaseC_kernel(
    const float* __restrict__ lw, const float* __restrict__ lb,
    const float* __restrict__ Hall, float* __restrict__ out)
{
    int t  = blockIdx.x >> 2;
    int v0 = (blockIdx.x & 3) << 5;
    int tid = threadIdx.x;
    int v  = v0 + (tid >> 3);
    int bg = tid & 7;
    const float* w  = lw + ((size_t)t * VV + v) * HH;
    const float* hp = Hall + (size_t)t * HH * BB;
    float acc0 = 0.f, acc1 = 0.f, acc2 = 0.f, acc3 = 0.f;
    #pragma unroll 4
    for (int k = 0; k < HH; ++k) {
        float wv = w[k];
        float4 hv = *reinterpret_cast<const float4*>(hp + (size_t)k * BB + bg * 4);
        acc0 = fmaf(wv, hv.x, acc0);
        acc1 = fmaf(wv, hv.y, acc1);
        acc2 = fmaf(wv, hv.z, acc2);
        acc3 = fmaf(wv, hv.w, acc3);
    }
    float bias = lb[t * VV + v];
    float r[4] = {acc0 + bias, acc1 + bias, acc2 + bias, acc3 + bias};
    #pragma unroll
    for (int j = 0; j < 4; ++j) {
        int b = bg * 4 + j;
        out[((size_t)b * TT + t) * VV + v] = r[j];
    }
}

extern "C" void kernel_launch(void* const* d_in, const int* in_sizes, int n_in,
                              void* d_out, int out_size, void* d_ws, size_t ws_size,
                              hipStream_t stream)
{
    const float* x     = (const float*)d_in[0];
    const float* Wif   = (const float*)d_in[1];
    const float* Wii   = (const float*)d_in[2];
    const float* Wic   = (const float*)d_in[3];
    const float* Wio   = (const float*)d_in[4];
    const float* Whf_w = (const float*)d_in[5];
    const float* Whf_b = (const float*)d_in[6];
    const float* Whi_w = (const float*)d_in[7];
    const float* Whi_b = (const float*)d_in[8];
    const float* Whc_w = (const float*)d_in[9];
    const float* Whc_b = (const float*)d_in[10];
    const float* Who_w = (const float*)d_in[11];
    const float* Who_b = (const float*)d_in[12];
    const float* lin_w = (const float*)d_in[13];
    const float* lin_b = (const float*)d_in[14];
    float* out = (float*)d_out;

    float* Z    = (float*)d_ws;                              // 96*4*512*32 floats
    float* Hall = Z + (size_t)TT * 4 * HH * BB;              // 96*512*32 floats

    phaseA_kernel<<<dim3(TT * 16), dim3(256), 0, stream>>>(x, Wif, Wii, Wic, Wio, Z);

    {
        const float* whf = Whf_w; const float* whi = Whi_w;
        const float* whc = Whc_w; const float* who = Who_w;
        const float* pbf = Whf_b; const float* pbi = Whi_b;
        const float* pbc = Whc_b; const float* pbo = Who_b;
        const float* pz  = Z;     float* ph = Hall;
        void* args[] = {&whf, &whi, &whc, &who, &pbf, &pbi, &pbc, &pbo, &pz, &ph};
        hipLaunchCooperativeKernel((void*)lstm_persistent, dim3(512), dim3(256),
                                   args, 0, stream);
    }

    phaseC_kernel<<<dim3(TT * 4), dim3(256), 0, stream>>>(lin_w, lin_b, Hall, out);
}

// Round 4
// 2901.776 us; speedup vs baseline: 3.5678x; 3.5678x over previous
//
#include <hip/hip_runtime.h>
#include <hip/hip_bf16.h>

#define TT 96
#define BB 32
#define DIN 256
#define HH 512
#define VV 128
#define NB 256   // persistent blocks (1 per CU)

// ---------------- Phase A: Z[t][g][h][b] = sum_d x[b][t][d] * Wg[t][h][d] ----------------
__global__ __launch_bounds__(256) void phaseA_kernel(
    const float* __restrict__ x,
    const float* __restrict__ Wf, const float* __restrict__ Wi,
    const float* __restrict__ Wc, const float* __restrict__ Wo,
    float* __restrict__ Z)
{
    int bid  = blockIdx.x;
    int t    = bid >> 4;
    int tile = bid & 15;
    int g    = tile >> 2;
    int h0   = (tile & 3) * 128;
    const float* W = (g == 0) ? Wf : (g == 1) ? Wi : (g == 2) ? Wc : Wo;

    __shared__ float4 Xs4[32 * 64];   // 32 KB; (b, q) at [b*64 + (q ^ (b&15))]
    __shared__ float4 Wc4[128 * 8];   // 16 KB; slot s=row*8+qs holds global quad qs ^ ((row>>2)&7)

    int tid = threadIdx.x;
    {
        int b   = tid >> 3;
        int kq8 = tid & 7;
        const float* src = x + ((size_t)b * TT + t) * DIN;
        int bx = b & 15;
        #pragma unroll
        for (int j = 0; j < 8; ++j) {
            int q = kq8 * 8 + j;
            Xs4[b * 64 + (q ^ bx)] = *reinterpret_cast<const float4*>(src + q * 4);
        }
    }

    int rg = tid >> 3;
    int bg = tid & 7;
    const float* wbase = W + ((size_t)t * HH + h0) * DIN;

    int srow[4], sgq[4];
    #pragma unroll
    for (int j = 0; j < 4; ++j) {
        int s = j * 256 + tid;
        srow[j] = s >> 3;
        sgq[j]  = (s & 7) ^ ((srow[j] >> 2) & 7);
    }

    float4 stg[4];
    #pragma unroll
    for (int j = 0; j < 4; ++j)
        stg[j] = *reinterpret_cast<const float4*>(wbase + (size_t)srow[j] * DIN + sgq[j] * 4);

    float acc[4][4];
    #pragma unroll
    for (int r = 0; r < 4; ++r)
        #pragma unroll
        for (int c = 0; c < 4; ++c) acc[r][c] = 0.f;

    for (int kc = 0; kc < 8; ++kc) {
        __syncthreads();
        #pragma unroll
        for (int j = 0; j < 4; ++j) Wc4[j * 256 + tid] = stg[j];
        __syncthreads();
        if (kc < 7) {
            #pragma unroll
            for (int j = 0; j < 4; ++j)
                stg[j] = *reinterpret_cast<const float4*>(
                    wbase + (size_t)srow[j] * DIN + (kc + 1) * 32 + sgq[j] * 4);
        }
        #pragma unroll
        for (int q = 0; q < 8; ++q) {
            float4 xv[4], wv[4];
            #pragma unroll
            for (int c = 0; c < 4; ++c) {
                int b = c * 8 + bg;
                xv[c] = Xs4[b * 64 + ((kc * 8 + q) ^ (b & 15))];
            }
            #pragma unroll
            for (int r = 0; r < 4; ++r)
                wv[r] = Wc4[(rg * 4 + r) * 8 + (q ^ (rg & 7))];
            #pragma unroll
            for (int r = 0; r < 4; ++r)
                #pragma unroll
                for (int c = 0; c < 4; ++c) {
                    acc[r][c] = fmaf(wv[r].x, xv[c].x, acc[r][c]);
                    acc[r][c] = fmaf(wv[r].y, xv[c].y, acc[r][c]);
                    acc[r][c] = fmaf(wv[r].z, xv[c].z, acc[r][c]);
                    acc[r][c] = fmaf(wv[r].w, xv[c].w, acc[r][c]);
                }
        }
    }

    size_t zbase = ((size_t)(t * 4 + g) * HH + h0 + rg * 4) * BB;
    #pragma unroll
    for (int r = 0; r < 4; ++r)
        #pragma unroll
        for (int c = 0; c < 4; ++c)
            Z[zbase + (size_t)r * BB + c * 8 + bg] = acc[r][c];
}

// ---------------- Phase B: persistent kernel with hand-rolled grid barrier ----------------
// 256 blocks (2 h-rows each) x 256 threads (16 k-chunks x 16 b-pairs).
__global__ __launch_bounds__(256) void lstm_persistent(
    const float* __restrict__ Whf, const float* __restrict__ Whi,
    const float* __restrict__ Whc, const float* __restrict__ Who,
    const float* __restrict__ bf,  const float* __restrict__ bi,
    const float* __restrict__ bc,  const float* __restrict__ bo,
    const float* __restrict__ Z,   float* __restrict__ Hall,
    unsigned* __restrict__ bar)
{
    int r0  = blockIdx.x * 2;
    int tid = threadIdx.x;
    int ks  = tid >> 4;          // 0..15, k-chunk of 32
    int bg  = tid & 15;          // b = 2bg, 2bg+1

    __shared__ float pre[16][8][32];   // [ks][rowloc*4+gate][b]  16 KB
    __shared__ float act[8][32];

    float creg = 0.f;            // tid<64: c for (row r0+(tid>>5), b=tid&31)

    for (int t = 0; t < TT; ++t) {
        float a[8][2];
        #pragma unroll
        for (int rg = 0; rg < 8; ++rg) { a[rg][0] = 0.f; a[rg][1] = 0.f; }

        if (t > 0) {
            int k0 = ks * 32;
            const float* hp = Hall + (size_t)(t - 1) * HH * BB + (size_t)k0 * BB + 2 * bg;
            const float* wp[8];
            #pragma unroll
            for (int rl = 0; rl < 2; ++rl) {
                size_t wo = ((size_t)t * HH + r0 + rl) * HH + k0;
                wp[rl * 4 + 0] = Whf + wo;
                wp[rl * 4 + 1] = Whi + wo;
                wp[rl * 4 + 2] = Whc + wo;
                wp[rl * 4 + 3] = Who + wo;
            }
            #pragma unroll
            for (int q = 0; q < 8; ++q) {
                float2 h0v = *reinterpret_cast<const float2*>(hp + (size_t)(q * 4 + 0) * BB);
                float2 h1v = *reinterpret_cast<const float2*>(hp + (size_t)(q * 4 + 1) * BB);
                float2 h2v = *reinterpret_cast<const float2*>(hp + (size_t)(q * 4 + 2) * BB);
                float2 h3v = *reinterpret_cast<const float2*>(hp + (size_t)(q * 4 + 3) * BB);
                #pragma unroll
                for (int rg = 0; rg < 8; ++rg) {
                    float4 w = *reinterpret_cast<const float4*>(wp[rg] + q * 4);
                    a[rg][0] = fmaf(w.x, h0v.x, a[rg][0]); a[rg][1] = fmaf(w.x, h0v.y, a[rg][1]);
                    a[rg][0] = fmaf(w.y, h1v.x, a[rg][0]); a[rg][1] = fmaf(w.y, h1v.y, a[rg][1]);
                    a[rg][0] = fmaf(w.z, h2v.x, a[rg][0]); a[rg][1] = fmaf(w.z, h2v.y, a[rg][1]);
                    a[rg][0] = fmaf(w.w, h3v.x, a[rg][0]); a[rg][1] = fmaf(w.w, h3v.y, a[rg][1]);
                }
            }
        }
        #pragma unroll
        for (int rg = 0; rg < 8; ++rg) {
            pre[ks][rg][2 * bg]     = a[rg][0];
            pre[ks][rg][2 * bg + 1] = a[rg][1];
        }

        // prefetch W[t+1] chunk for this block into regs (keeps IC/L2 warm)
        float pf0 = 0.f, pf1 = 0.f, pf2 = 0.f, pf3 = 0.f;
        float4 pfv[4];
        bool do_pf = (t + 1 < TT);
        if (do_pf) {
            #pragma unroll
            for (int j = 0; j < 4; ++j) {
                int f    = j * 256 + tid;       // 0..1023 float4s
                int gate = f >> 8;
                int rl   = (f >> 7) & 1;
                int q    = f & 127;
                const float* wsrc = ((gate == 0) ? Whf : (gate == 1) ? Whi :
                                     (gate == 2) ? Whc : Who)
                                    + ((size_t)(t + 1) * HH + r0 + rl) * HH + q * 4;
                pfv[j] = *reinterpret_cast<const float4*>(wsrc);
            }
        }

        __syncthreads();

        {
            int rg2 = tid >> 5;          // rowloc*4+gate
            int b   = tid & 31;
            int row = r0 + (rg2 >> 2);
            int g   = rg2 & 3;
            float s = 0.f;
            #pragma unroll
            for (int k2 = 0; k2 < 16; ++k2) s += pre[k2][rg2][b];
            s += Z[((size_t)(t * 4 + g) * HH + row) * BB + b];
            if (t > 0) {
                const float* bp = (g == 0) ? bf : (g == 1) ? bi : (g == 2) ? bc : bo;
                s += bp[t * HH + row];
            }
            act[rg2][b] = (g == 2) ? tanhf(s) : 1.f / (1.f + __expf(-s));
        }
        __syncthreads();

        if (tid < 64) {
            int rl = tid >> 5, b = tid & 31;
            float cn = act[rl * 4 + 0][b] * creg + act[rl * 4 + 1][b] * act[rl * 4 + 2][b];
            creg = cn;
            Hall[((size_t)t * HH + r0 + rl) * BB + b] = act[rl * 4 + 3][b] * tanhf(cn);
        }
        __syncthreads();                 // h writes done; pre[]/act[] free for reuse

        if (t + 1 < TT) {
            // consume prefetch regs (loads have completed by now; keeps them un-DCE'd)
            if (do_pf) {
                pf0 = pfv[0].x + pfv[1].x + pfv[2].x + pfv[3].x;
                pf1 = pfv[0].y + pfv[1].y + pfv[2].y + pfv[3].y;
                pf2 = pfv[0].z + pfv[1].z + pfv[2].z + pfv[3].z;
                pf3 = pfv[0].w + pfv[1].w + pfv[2].w + pfv[3].w;
                asm volatile("" :: "v"(pf0), "v"(pf1), "v"(pf2), "v"(pf3));
            }
            if (tid == 0) {
                __threadfence();         // release: flush local L2 dirty lines (our h rows)
                unsigned prev = __hip_atomic_fetch_add(&bar[t * 16], 1u,
                                    __ATOMIC_RELAXED, __HIP_MEMORY_SCOPE_AGENT);
                if (prev + 1 < (unsigned)NB) {
                    while (__hip_atomic_load(&bar[t * 16], __ATOMIC_RELAXED,
                                             __HIP_MEMORY_SCOPE_AGENT) < (unsigned)NB)
                        __builtin_amdgcn_s_sleep(2);
                }
            }
            __syncthreads();
            __threadfence();             // acquire: invalidate local L2 -> fresh h reads
        }
    }
}

// ---------------- Phase C ----------------
__global__ __launch_bounds__(256) void phaseC_kernel(
    const float* __restrict__ lw, const float* __restrict__ lb,
    const float* __restrict__ Hall, float* __restrict__ out)
{
    int t  = blockIdx.x >> 2;
    int v0 = (blockIdx.x & 3) << 5;
    int tid = threadIdx.x;
    int v  = v0 + (tid >> 3);
    int bg = tid & 7;
    const float* w  = lw + ((size_t)t * VV + v) * HH;
    const float* hp = Hall + (size_t)t * HH * BB;
    float acc0 = 0.f, acc1 = 0.f, acc2 = 0.f, acc3 = 0.f;
    #pragma unroll 4
    for (int k = 0; k < HH; ++k) {
        float wv = w[k];
        float4 hv = *reinterpret_cast<const float4*>(hp + (size_t)k * BB + bg * 4);
        acc0 = fmaf(wv, hv.x, acc0);
        acc1 = fmaf(wv, hv.y, acc1);
        acc2 = fmaf(wv, hv.z, acc2);
        acc3 = fmaf(wv, hv.w, acc3);
    }
    float bias = lb[t * VV + v];
    float r[4] = {acc0 + bias, acc1 + bias, acc2 + bias, acc3 + bias};
    #pragma unroll
    for (int j = 0; j < 4; ++j) {
        int b = bg * 4 + j;
        out[((size_t)b * TT + t) * VV + v] = r[j];
    }
}

extern "C" void kernel_launch(void* const* d_in, const int* in_sizes, int n_in,
                              void* d_out, int out_size, void* d_ws, size_t ws_size,
                              hipStream_t stream)
{
    const float* x     = (const float*)d_in[0];
    const float* Wif   = (const float*)d_in[1];
    const float* Wii   = (const float*)d_in[2];
    const float* Wic   = (const float*)d_in[3];
    const float* Wio   = (const float*)d_in[4];
    const float* Whf_w = (const float*)d_in[5];
    const float* Whf_b = (const float*)d_in[6];
    const float* Whi_w = (const float*)d_in[7];
    const float* Whi_b = (const float*)d_in[8];
    const float* Whc_w = (const float*)d_in[9];
    const float* Whc_b = (const float*)d_in[10];
    const float* Who_w = (const float*)d_in[11];
    const float* Who_b = (const float*)d_in[12];
    const float* lin_w = (const float*)d_in[13];
    const float* lin_b = (const float*)d_in[14];
    float* out = (float*)d_out;

    float*    Z    = (float*)d_ws;                           // 96*4*512*32 floats
    float*    Hall = Z + (size_t)TT * 4 * HH * BB;           // 96*512*32 floats
    unsigned* bar  = (unsigned*)(Hall + (size_t)TT * HH * BB);  // 96*16 uints (64B stride)

    hipMemsetAsync(bar, 0, TT * 16 * sizeof(unsigned), stream);

    phaseA_kernel<<<dim3(TT * 16), dim3(256), 0, stream>>>(x, Wif, Wii, Wic, Wio, Z);

    lstm_persistent<<<dim3(NB), dim3(256), 0, stream>>>(
        Whf_w, Whi_w, Whc_w, Who_w, Whf_b, Whi_b, Whc_b, Who_b, Z, Hall, bar);

    phaseC_kernel<<<dim3(TT * 4), dim3(256), 0, stream>>>(lin_w, lin_b, Hall, out);
}

// Round 5
// 1096.152 us; speedup vs baseline: 9.4448x; 2.6472x over previous
//
#include <hip/hip_runtime.h>
#include <hip/hip_bf16.h>

#define TT 96
#define BB 32
#define DIN 256
#define HH 512
#define VV 128
#define NB 256   // persistent blocks (1 per CU)

// ---------------- Phase A: Z[t][g][h][b] = sum_d x[b][t][d] * Wg[t][h][d] ----------------
__global__ __launch_bounds__(256) void phaseA_kernel(
    const float* __restrict__ x,
    const float* __restrict__ Wf, const float* __restrict__ Wi,
    const float* __restrict__ Wc, const float* __restrict__ Wo,
    float* __restrict__ Z)
{
    int bid  = blockIdx.x;
    int t    = bid >> 4;
    int tile = bid & 15;
    int g    = tile >> 2;
    int h0   = (tile & 3) * 128;
    const float* W = (g == 0) ? Wf : (g == 1) ? Wi : (g == 2) ? Wc : Wo;

    __shared__ float4 Xs4[32 * 64];   // 32 KB; (b, q) at [b*64 + (q ^ (b&15))]
    __shared__ float4 Wc4[128 * 8];   // 16 KB; slot s=row*8+qs holds global quad qs ^ ((row>>2)&7)

    int tid = threadIdx.x;
    {
        int b   = tid >> 3;
        int kq8 = tid & 7;
        const float* src = x + ((size_t)b * TT + t) * DIN;
        int bx = b & 15;
        #pragma unroll
        for (int j = 0; j < 8; ++j) {
            int q = kq8 * 8 + j;
            Xs4[b * 64 + (q ^ bx)] = *reinterpret_cast<const float4*>(src + q * 4);
        }
    }

    int rg = tid >> 3;
    int bg = tid & 7;
    const float* wbase = W + ((size_t)t * HH + h0) * DIN;

    int srow[4], sgq[4];
    #pragma unroll
    for (int j = 0; j < 4; ++j) {
        int s = j * 256 + tid;
        srow[j] = s >> 3;
        sgq[j]  = (s & 7) ^ ((srow[j] >> 2) & 7);
    }

    float4 stg[4];
    #pragma unroll
    for (int j = 0; j < 4; ++j)
        stg[j] = *reinterpret_cast<const float4*>(wbase + (size_t)srow[j] * DIN + sgq[j] * 4);

    float acc[4][4];
    #pragma unroll
    for (int r = 0; r < 4; ++r)
        #pragma unroll
        for (int c = 0; c < 4; ++c) acc[r][c] = 0.f;

    for (int kc = 0; kc < 8; ++kc) {
        __syncthreads();
        #pragma unroll
        for (int j = 0; j < 4; ++j) Wc4[j * 256 + tid] = stg[j];
        __syncthreads();
        if (kc < 7) {
            #pragma unroll
            for (int j = 0; j < 4; ++j)
                stg[j] = *reinterpret_cast<const float4*>(
                    wbase + (size_t)srow[j] * DIN + (kc + 1) * 32 + sgq[j] * 4);
        }
        #pragma unroll
        for (int q = 0; q < 8; ++q) {
            float4 xv[4], wv[4];
            #pragma unroll
            for (int c = 0; c < 4; ++c) {
                int b = c * 8 + bg;
                xv[c] = Xs4[b * 64 + ((kc * 8 + q) ^ (b & 15))];
            }
            #pragma unroll
            for (int r = 0; r < 4; ++r)
                wv[r] = Wc4[(rg * 4 + r) * 8 + (q ^ (rg & 7))];
            #pragma unroll
            for (int r = 0; r < 4; ++r)
                #pragma unroll
                for (int c = 0; c < 4; ++c) {
                    acc[r][c] = fmaf(wv[r].x, xv[c].x, acc[r][c]);
                    acc[r][c] = fmaf(wv[r].y, xv[c].y, acc[r][c]);
                    acc[r][c] = fmaf(wv[r].z, xv[c].z, acc[r][c]);
                    acc[r][c] = fmaf(wv[r].w, xv[c].w, acc[r][c]);
                }
        }
    }

    size_t zbase = ((size_t)(t * 4 + g) * HH + h0 + rg * 4) * BB;
    #pragma unroll
    for (int r = 0; r < 4; ++r)
        #pragma unroll
        for (int c = 0; c < 4; ++c)
            Z[zbase + (size_t)r * BB + c * 8 + bg] = acc[r][c];
}

// ---------------- Phase B: persistent kernel, tree barrier, IC-bypass h exchange ----------
// 256 blocks (2 h-rows each) x 512 threads (32 k-chunks of 16 x 16 b-pairs).
__global__ __launch_bounds__(512) void lstm_persistent(
    const float* __restrict__ Whf, const float* __restrict__ Whi,
    const float* __restrict__ Whc, const float* __restrict__ Who,
    const float* __restrict__ bf,  const float* __restrict__ bi,
    const float* __restrict__ bc,  const float* __restrict__ bo,
    const float* __restrict__ Z,   float* __restrict__ Hall,
    unsigned* __restrict__ bar)
{
    int blk = blockIdx.x;
    int r0  = blk * 2;
    int gid = blk >> 4;          // barrier group 0..15
    int tid = threadIdx.x;
    int ks  = tid >> 4;          // 0..31, k-chunk of 16
    int bg  = tid & 15;          // b = 2bg, 2bg+1

    __shared__ float pre[32][8][32];   // [ks][rowloc*4+gate][b]  32 KB
    __shared__ float act[8][32];

    float creg = 0.f;            // tid<64: c for (row r0+(tid>>5), b=tid&31)

    for (int t = 0; t < TT; ++t) {
        float a[8][2];
        #pragma unroll
        for (int rg = 0; rg < 8; ++rg) { a[rg][0] = 0.f; a[rg][1] = 0.f; }

        if (t > 0) {
            int k0 = ks * 16;
            const float* hbase = Hall + (size_t)(t - 1) * HH * BB + (size_t)k0 * BB + 2 * bg;
            const float* wp[8];
            #pragma unroll
            for (int rl = 0; rl < 2; ++rl) {
                size_t wo = ((size_t)t * HH + r0 + rl) * HH + k0;
                wp[rl * 4 + 0] = Whf + wo;
                wp[rl * 4 + 1] = Whi + wo;
                wp[rl * 4 + 2] = Whc + wo;
                wp[rl * 4 + 3] = Who + wo;
            }
            #pragma unroll
            for (int q = 0; q < 4; ++q) {
                float2 hv[4];
                #pragma unroll
                for (int j = 0; j < 4; ++j) {
                    unsigned long long u = __hip_atomic_load(
                        (unsigned long long*)(hbase + (size_t)(q * 4 + j) * BB),
                        __ATOMIC_RELAXED, __HIP_MEMORY_SCOPE_AGENT);
                    hv[j].x = __uint_as_float((unsigned)u);
                    hv[j].y = __uint_as_float((unsigned)(u >> 32));
                }
                #pragma unroll
                for (int rg = 0; rg < 8; ++rg) {
                    float4 w = *reinterpret_cast<const float4*>(wp[rg] + q * 4);
                    a[rg][0] = fmaf(w.x, hv[0].x, a[rg][0]); a[rg][1] = fmaf(w.x, hv[0].y, a[rg][1]);
                    a[rg][0] = fmaf(w.y, hv[1].x, a[rg][0]); a[rg][1] = fmaf(w.y, hv[1].y, a[rg][1]);
                    a[rg][0] = fmaf(w.z, hv[2].x, a[rg][0]); a[rg][1] = fmaf(w.z, hv[2].y, a[rg][1]);
                    a[rg][0] = fmaf(w.w, hv[3].x, a[rg][0]); a[rg][1] = fmaf(w.w, hv[3].y, a[rg][1]);
                }
            }
        }
        #pragma unroll
        for (int rg = 0; rg < 8; ++rg) {
            pre[ks][rg][2 * bg]     = a[rg][0];
            pre[ks][rg][2 * bg + 1] = a[rg][1];
        }

        // prefetch W[t+1] rows for this block into L1/L2 via plain cached loads
        float4 pfv[2];
        bool do_pf = (t + 1 < TT);
        if (do_pf) {
            #pragma unroll
            for (int j = 0; j < 2; ++j) {
                int f    = j * 512 + tid;       // 0..1023 float4s
                int gate = f >> 8;
                int rl   = (f >> 7) & 1;
                int q    = f & 127;
                const float* wsrc = ((gate == 0) ? Whf : (gate == 1) ? Whi :
                                     (gate == 2) ? Whc : Who)
                                    + ((size_t)(t + 1) * HH + r0 + rl) * HH + q * 4;
                pfv[j] = *reinterpret_cast<const float4*>(wsrc);
            }
        }

        __syncthreads();

        if (tid < 256) {
            int rg2 = tid >> 5;          // rowloc*4+gate
            int b   = tid & 31;
            int row = r0 + (rg2 >> 2);
            int g   = rg2 & 3;
            float s = 0.f;
            #pragma unroll
            for (int k2 = 0; k2 < 32; ++k2) s += pre[k2][rg2][b];
            s += Z[((size_t)(t * 4 + g) * HH + row) * BB + b];
            if (t > 0) {
                const float* bp = (g == 0) ? bf : (g == 1) ? bi : (g == 2) ? bc : bo;
                s += bp[t * HH + row];
            }
            act[rg2][b] = (g == 2) ? tanhf(s) : 1.f / (1.f + __expf(-s));
        }
        __syncthreads();

        if (tid < 64) {
            int rl = tid >> 5, b = tid & 31;
            float cn = act[rl * 4 + 0][b] * creg + act[rl * 4 + 1][b] * act[rl * 4 + 2][b];
            creg = cn;
            float hn = act[rl * 4 + 3][b] * tanhf(cn);
            // write-through to IC (bypasses L2) -> visible to all XCDs without fences
            __hip_atomic_store(Hall + ((size_t)t * HH + r0 + rl) * BB + b, hn,
                               __ATOMIC_RELAXED, __HIP_MEMORY_SCOPE_AGENT);
        }

        if (t + 1 < TT) {
            // consume prefetch (forces the loads to land in L1/L2 before next step)
            float pf0 = pfv[0].x + pfv[1].x, pf1 = pfv[0].y + pfv[1].y;
            float pf2 = pfv[0].z + pfv[1].z, pf3 = pfv[0].w + pfv[1].w;
            asm volatile("" :: "v"(pf0), "v"(pf1), "v"(pf2), "v"(pf3));
            // each wave drains its own VMEM (h stores at IC, prefetch complete)
            asm volatile("s_waitcnt vmcnt(0)" ::: "memory");
            __syncthreads();

            if (tid == 0) {
                unsigned* grp  = bar + ((size_t)t * 32 + gid) * 16;
                unsigned* root = bar + ((size_t)t * 32 + 16) * 16;
                unsigned* flag = bar + ((size_t)t * 32 + 17) * 16;
                unsigned prev = __hip_atomic_fetch_add(grp, 1u, __ATOMIC_RELAXED,
                                                       __HIP_MEMORY_SCOPE_AGENT);
                if (prev == 15u) {
                    unsigned p2 = __hip_atomic_fetch_add(root, 1u, __ATOMIC_RELAXED,
                                                         __HIP_MEMORY_SCOPE_AGENT);
                    if (p2 == 15u)
                        __hip_atomic_store(flag, 1u, __ATOMIC_RELAXED,
                                           __HIP_MEMORY_SCOPE_AGENT);
                }
                while (__hip_atomic_load(flag, __ATOMIC_RELAXED,
                                         __HIP_MEMORY_SCOPE_AGENT) == 0u)
                    __builtin_amdgcn_s_sleep(4);
            }
            __syncthreads();
        }
    }
}

// ---------------- Phase C ----------------
__global__ __launch_bounds__(256) void phaseC_kernel(
    const float* __restrict__ lw, const float* __restrict__ lb,
    const float* __restrict__ Hall, float* __restrict__ out)
{
    int t  = blockIdx.x >> 2;
    int v0 = (blockIdx.x & 3) << 5;
    int tid = threadIdx.x;
    int v  = v0 + (tid >> 3);
    int bg = tid & 7;
    const float* w  = lw + ((size_t)t * VV + v) * HH;
    const float* hp = Hall + (size_t)t * HH * BB;
    float acc0 = 0.f, acc1 = 0.f, acc2 = 0.f, acc3 = 0.f;
    #pragma unroll 4
    for (int k = 0; k < HH; ++k) {
        float wv = w[k];
        float4 hv = *reinterpret_cast<const float4*>(hp + (size_t)k * BB + bg * 4);
        acc0 = fmaf(wv, hv.x, acc0);
        acc1 = fmaf(wv, hv.y, acc1);
        acc2 = fmaf(wv, hv.z, acc2);
        acc3 = fmaf(wv, hv.w, acc3);
    }
    float bias = lb[t * VV + v];
    float r[4] = {acc0 + bias, acc1 + bias, acc2 + bias, acc3 + bias};
    #pragma unroll
    for (int j = 0; j < 4; ++j) {
        int b = bg * 4 + j;
        out[((size_t)b * TT + t) * VV + v] = r[j];
    }
}

extern "C" void kernel_launch(void* const* d_in, const int* in_sizes, int n_in,
                              void* d_out, int out_size, void* d_ws, size_t ws_size,
                              hipStream_t stream)
{
    const float* x     = (const float*)d_in[0];
    const float* Wif   = (const float*)d_in[1];
    const float* Wii   = (const float*)d_in[2];
    const float* Wic   = (const float*)d_in[3];
    const float* Wio   = (const float*)d_in[4];
    const float* Whf_w = (const float*)d_in[5];
    const float* Whf_b = (const float*)d_in[6];
    const float* Whi_w = (const float*)d_in[7];
    const float* Whi_b = (const float*)d_in[8];
    const float* Whc_w = (const float*)d_in[9];
    const float* Whc_b = (const float*)d_in[10];
    const float* Who_w = (const float*)d_in[11];
    const float* Who_b = (const float*)d_in[12];
    const float* lin_w = (const float*)d_in[13];
    const float* lin_b = (const float*)d_in[14];
    float* out = (float*)d_out;

    float*    Z    = (float*)d_ws;                           // 96*4*512*32 floats
    float*    Hall = Z + (size_t)TT * 4 * HH * BB;           // 96*512*32 floats
    unsigned* bar  = (unsigned*)(Hall + (size_t)TT * HH * BB);  // 96*32 counters, 64B apart

    hipMemsetAsync(bar, 0, (size_t)TT * 32 * 16 * sizeof(unsigned), stream);

    phaseA_kernel<<<dim3(TT * 16), dim3(256), 0, stream>>>(x, Wif, Wii, Wic, Wio, Z);

    lstm_persistent<<<dim3(NB), dim3(512), 0, stream>>>(
        Whf_w, Whi_w, Whc_w, Who_w, Whf_b, Whi_b, Whc_b, Who_b, Z, Hall, bar);

    phaseC_kernel<<<dim3(TT * 4), dim3(256), 0, stream>>>(lin_w, lin_b, Hall, out);
}

// Round 6
// 990.188 us; speedup vs baseline: 10.4555x; 1.1070x over previous
//
#include <hip/hip_runtime.h>
#include <hip/hip_bf16.h>

#define TT 96
#define BB 32
#define DIN 256
#define HH 512
#define VV 128
#define NB 256   // persistent blocks (1 per CU)

// ---------------- Phase A: Z[t][g][h][b] = sum_d x[b][t][d] * Wg[t][h][d] ----------------
__global__ __launch_bounds__(256) void phaseA_kernel(
    const float* __restrict__ x,
    const float* __restrict__ Wf, const float* __restrict__ Wi,
    const float* __restrict__ Wc, const float* __restrict__ Wo,
    float* __restrict__ Z)
{
    int bid  = blockIdx.x;
    int t    = bid >> 4;
    int tile = bid & 15;
    int g    = tile >> 2;
    int h0   = (tile & 3) * 128;
    const float* W = (g == 0) ? Wf : (g == 1) ? Wi : (g == 2) ? Wc : Wo;

    __shared__ float4 Xs4[32 * 64];   // 32 KB; (b, q) at [b*64 + (q ^ (b&15))]
    __shared__ float4 Wc4[128 * 8];   // 16 KB; slot s=row*8+qs holds global quad qs ^ ((row>>2)&7)

    int tid = threadIdx.x;
    {
        int b   = tid >> 3;
        int kq8 = tid & 7;
        const float* src = x + ((size_t)b * TT + t) * DIN;
        int bx = b & 15;
        #pragma unroll
        for (int j = 0; j < 8; ++j) {
            int q = kq8 * 8 + j;
            Xs4[b * 64 + (q ^ bx)] = *reinterpret_cast<const float4*>(src + q * 4);
        }
    }

    int rg = tid >> 3;
    int bg = tid & 7;
    const float* wbase = W + ((size_t)t * HH + h0) * DIN;

    int srow[4], sgq[4];
    #pragma unroll
    for (int j = 0; j < 4; ++j) {
        int s = j * 256 + tid;
        srow[j] = s >> 3;
        sgq[j]  = (s & 7) ^ ((srow[j] >> 2) & 7);
    }

    float4 stg[4];
    #pragma unroll
    for (int j = 0; j < 4; ++j)
        stg[j] = *reinterpret_cast<const float4*>(wbase + (size_t)srow[j] * DIN + sgq[j] * 4);

    float acc[4][4];
    #pragma unroll
    for (int r = 0; r < 4; ++r)
        #pragma unroll
        for (int c = 0; c < 4; ++c) acc[r][c] = 0.f;

    for (int kc = 0; kc < 8; ++kc) {
        __syncthreads();
        #pragma unroll
        for (int j = 0; j < 4; ++j) Wc4[j * 256 + tid] = stg[j];
        __syncthreads();
        if (kc < 7) {
            #pragma unroll
            for (int j = 0; j < 4; ++j)
                stg[j] = *reinterpret_cast<const float4*>(
                    wbase + (size_t)srow[j] * DIN + (kc + 1) * 32 + sgq[j] * 4);
        }
        #pragma unroll
        for (int q = 0; q < 8; ++q) {
            float4 xv[4], wv[4];
            #pragma unroll
            for (int c = 0; c < 4; ++c) {
                int b = c * 8 + bg;
                xv[c] = Xs4[b * 64 + ((kc * 8 + q) ^ (b & 15))];
            }
            #pragma unroll
            for (int r = 0; r < 4; ++r)
                wv[r] = Wc4[(rg * 4 + r) * 8 + (q ^ (rg & 7))];
            #pragma unroll
            for (int r = 0; r < 4; ++r)
                #pragma unroll
                for (int c = 0; c < 4; ++c) {
                    acc[r][c] = fmaf(wv[r].x, xv[c].x, acc[r][c]);
                    acc[r][c] = fmaf(wv[r].y, xv[c].y, acc[r][c]);
                    acc[r][c] = fmaf(wv[r].z, xv[c].z, acc[r][c]);
                    acc[r][c] = fmaf(wv[r].w, xv[c].w, acc[r][c]);
                }
        }
    }

    size_t zbase = ((size_t)(t * 4 + g) * HH + h0 + rg * 4) * BB;
    #pragma unroll
    for (int r = 0; r < 4; ++r)
        #pragma unroll
        for (int c = 0; c < 4; ++c)
            Z[zbase + (size_t)r * BB + c * 8 + bg] = acc[r][c];
}

// ---------------- Phase B: persistent kernel, tree barrier, cached h reads ----------------
// 256 blocks (2 h-rows each) x 512 threads (32 k-chunks of 16 x 16 b-pairs).
// h stores: agent-scope sc1 (write-through to IC). h loads: plain cached (safe:
// L2 invalidated at dispatch; Hall[t] lines first touched only after the barrier,
// so every XCD's first access misses to IC which holds the fresh value; 32 blocks
// per XCD then share the line in L2).
__global__ __launch_bounds__(512) void lstm_persistent(
    const float* __restrict__ Whf, const float* __restrict__ Whi,
    const float* __restrict__ Whc, const float* __restrict__ Who,
    const float* __restrict__ bf,  const float* __restrict__ bi,
    const float* __restrict__ bc,  const float* __restrict__ bo,
    const float* __restrict__ Z,   float* __restrict__ Hall,
    unsigned* __restrict__ bar)
{
    int blk = blockIdx.x;
    int r0  = blk * 2;
    int gid = blk >> 4;          // barrier group 0..15
    int tid = threadIdx.x;
    int ks  = tid >> 4;          // 0..31, k-chunk of 16
    int bg  = tid & 15;          // b = 2bg, 2bg+1

    __shared__ float pre[32][8][32];   // [ks][rowloc*4+gate][b]  32 KB
    __shared__ float act[8][32];

    float creg = 0.f;            // tid<64: c for (row r0+(tid>>5), b=tid&31)

    for (int t = 0; t < TT; ++t) {
        float a[8][2];
        #pragma unroll
        for (int rg = 0; rg < 8; ++rg) { a[rg][0] = 0.f; a[rg][1] = 0.f; }

        if (t > 0) {
            int k0 = ks * 16;
            const float* hbase = Hall + (size_t)(t - 1) * HH * BB + (size_t)k0 * BB + 2 * bg;
            const float* wp[8];
            #pragma unroll
            for (int rl = 0; rl < 2; ++rl) {
                size_t wo = ((size_t)t * HH + r0 + rl) * HH + k0;
                wp[rl * 4 + 0] = Whf + wo;
                wp[rl * 4 + 1] = Whi + wo;
                wp[rl * 4 + 2] = Whc + wo;
                wp[rl * 4 + 3] = Who + wo;
            }
            #pragma unroll
            for (int q = 0; q < 4; ++q) {
                float2 hv[4];
                #pragma unroll
                for (int j = 0; j < 4; ++j)
                    hv[j] = *reinterpret_cast<const float2*>(hbase + (size_t)(q * 4 + j) * BB);
                #pragma unroll
                for (int rg = 0; rg < 8; ++rg) {
                    float4 w = *reinterpret_cast<const float4*>(wp[rg] + q * 4);
                    a[rg][0] = fmaf(w.x, hv[0].x, a[rg][0]); a[rg][1] = fmaf(w.x, hv[0].y, a[rg][1]);
                    a[rg][0] = fmaf(w.y, hv[1].x, a[rg][0]); a[rg][1] = fmaf(w.y, hv[1].y, a[rg][1]);
                    a[rg][0] = fmaf(w.z, hv[2].x, a[rg][0]); a[rg][1] = fmaf(w.z, hv[2].y, a[rg][1]);
                    a[rg][0] = fmaf(w.w, hv[3].x, a[rg][0]); a[rg][1] = fmaf(w.w, hv[3].y, a[rg][1]);
                }
            }
        }
        #pragma unroll
        for (int rg = 0; rg < 8; ++rg) {
            pre[ks][rg][2 * bg]     = a[rg][0];
            pre[ks][rg][2 * bg + 1] = a[rg][1];
        }

        // prefetch next step's W rows, Z rows, biases into L1/L2 (cached loads;
        // consumed AFTER the barrier so fill latency overlaps the barrier wait)
        float4 pfv[2];
        float4 pfz;
        float  pfb;
        bool do_pf = (t + 1 < TT);
        if (do_pf) {
            #pragma unroll
            for (int j = 0; j < 2; ++j) {
                int f    = j * 512 + tid;       // 0..1023 float4s
                int gate = f >> 8;
                int rl   = (f >> 7) & 1;
                int q    = f & 127;
                const float* wsrc = ((gate == 0) ? Whf : (gate == 1) ? Whi :
                                     (gate == 2) ? Whc : Who)
                                    + ((size_t)(t + 1) * HH + r0 + rl) * HH + q * 4;
                pfv[j] = *reinterpret_cast<const float4*>(wsrc);
            }
            if (tid < 64) {
                int g2 = tid >> 4, rl = (tid >> 3) & 1, qq = tid & 7;
                pfz = *reinterpret_cast<const float4*>(
                    Z + ((size_t)((t + 1) * 4 + g2) * HH + r0 + rl) * BB + qq * 4);
            }
            if (tid < 8) {
                int g2 = tid >> 1, rl = tid & 1;
                const float* bp = (g2 == 0) ? bf : (g2 == 1) ? bi : (g2 == 2) ? bc : bo;
                pfb = bp[(size_t)(t + 1) * HH + r0 + rl];
            }
        }

        __syncthreads();

        if (tid < 256) {
            int rg2 = tid >> 5;          // rowloc*4+gate
            int b   = tid & 31;
            int row = r0 + (rg2 >> 2);
            int g   = rg2 & 3;
            float s = 0.f;
            #pragma unroll
            for (int k2 = 0; k2 < 32; ++k2) s += pre[k2][rg2][b];
            s += Z[((size_t)(t * 4 + g) * HH + row) * BB + b];
            if (t > 0) {
                const float* bp = (g == 0) ? bf : (g == 1) ? bi : (g == 2) ? bc : bo;
                s += bp[t * HH + row];
            }
            act[rg2][b] = (g == 2) ? tanhf(s) : 1.f / (1.f + __expf(-s));
        }
        __syncthreads();

        if (tid < 64) {
            int rl = tid >> 5, b = tid & 31;
            float cn = act[rl * 4 + 0][b] * creg + act[rl * 4 + 1][b] * act[rl * 4 + 2][b];
            creg = cn;
            float hn = act[rl * 4 + 3][b] * tanhf(cn);
            // write-through to IC (visible to all XCDs without fences)
            __hip_atomic_store(Hall + ((size_t)t * HH + r0 + rl) * BB + b, hn,
                               __ATOMIC_RELAXED, __HIP_MEMORY_SCOPE_AGENT);
        }

        if (t + 1 < TT) {
            // wave 0 (tids 0..63) holds the h stores: drain them before arrival.
            if (tid < 64)
                asm volatile("s_waitcnt vmcnt(0)" ::: "memory");
            if (tid == 0) {
                unsigned* grp  = bar + ((size_t)t * 32 + gid) * 16;
                unsigned* root = bar + ((size_t)t * 32 + 16) * 16;
                unsigned* flag = bar + ((size_t)t * 32 + 17) * 16;
                unsigned prev = __hip_atomic_fetch_add(grp, 1u, __ATOMIC_RELAXED,
                                                       __HIP_MEMORY_SCOPE_AGENT);
                if (prev == 15u) {
                    unsigned p2 = __hip_atomic_fetch_add(root, 1u, __ATOMIC_RELAXED,
                                                         __HIP_MEMORY_SCOPE_AGENT);
                    if (p2 == 15u)
                        __hip_atomic_store(flag, 1u, __ATOMIC_RELAXED,
                                           __HIP_MEMORY_SCOPE_AGENT);
                }
                while (__hip_atomic_load(flag, __ATOMIC_RELAXED,
                                         __HIP_MEMORY_SCOPE_AGENT) == 0u)
                    __builtin_amdgcn_s_sleep(1);
            }
            __syncthreads();
            // consume prefetches AFTER the barrier: their fill overlapped the wait
            if (do_pf) {
                float k0s = pfv[0].x + pfv[1].x;
                float k1s = pfv[0].y + pfv[1].y;
                float k2s = pfv[0].z + pfv[1].z;
                float k3s = pfv[0].w + pfv[1].w;
                asm volatile("" :: "v"(k0s), "v"(k1s), "v"(k2s), "v"(k3s));
                if (tid < 64)
                    asm volatile("" :: "v"(pfz.x + pfz.w));
                if (tid < 8)
                    asm volatile("" :: "v"(pfb));
            }
        }
    }
}

// ---------------- Phase C ----------------
__global__ __launch_bounds__(256) void phaseC_kernel(
    const float* __restrict__ lw, const float* __restrict__ lb,
    const float* __restrict__ Hall, float* __restrict__ out)
{
    int t  = blockIdx.x >> 2;
    int v0 = (blockIdx.x & 3) << 5;
    int tid = threadIdx.x;
    int v  = v0 + (tid >> 3);
    int bg = tid & 7;
    const float* w  = lw + ((size_t)t * VV + v) * HH;
    const float* hp = Hall + (size_t)t * HH * BB;
    float acc0 = 0.f, acc1 = 0.f, acc2 = 0.f, acc3 = 0.f;
    #pragma unroll 4
    for (int k = 0; k < HH; ++k) {
        float wv = w[k];
        float4 hv = *reinterpret_cast<const float4*>(hp + (size_t)k * BB + bg * 4);
        acc0 = fmaf(wv, hv.x, acc0);
        acc1 = fmaf(wv, hv.y, acc1);
        acc2 = fmaf(wv, hv.z, acc2);
        acc3 = fmaf(wv, hv.w, acc3);
    }
    float bias = lb[t * VV + v];
    float r[4] = {acc0 + bias, acc1 + bias, acc2 + bias, acc3 + bias};
    #pragma unroll
    for (int j = 0; j < 4; ++j) {
        int b = bg * 4 + j;
        out[((size_t)b * TT + t) * VV + v] = r[j];
    }
}

extern "C" void kernel_launch(void* const* d_in, const int* in_sizes, int n_in,
                              void* d_out, int out_size, void* d_ws, size_t ws_size,
                              hipStream_t stream)
{
    const float* x     = (const float*)d_in[0];
    const float* Wif   = (const float*)d_in[1];
    const float* Wii   = (const float*)d_in[2];
    const float* Wic   = (const float*)d_in[3];
    const float* Wio   = (const float*)d_in[4];
    const float* Whf_w = (const float*)d_in[5];
    const float* Whf_b = (const float*)d_in[6];
    const float* Whi_w = (const float*)d_in[7];
    const float* Whi_b = (const float*)d_in[8];
    const float* Whc_w = (const float*)d_in[9];
    const float* Whc_b = (const float*)d_in[10];
    const float* Who_w = (const float*)d_in[11];
    const float* Who_b = (const float*)d_in[12];
    const float* lin_w = (const float*)d_in[13];
    const float* lin_b = (const float*)d_in[14];
    float* out = (float*)d_out;

    float*    Z    = (float*)d_ws;                           // 96*4*512*32 floats
    float*    Hall = Z + (size_t)TT * 4 * HH * BB;           // 96*512*32 floats
    unsigned* bar  = (unsigned*)(Hall + (size_t)TT * HH * BB);  // 96*32 counters, 64B apart

    hipMemsetAsync(bar, 0, (size_t)TT * 32 * 16 * sizeof(unsigned), stream);

    phaseA_kernel<<<dim3(TT * 16), dim3(256), 0, stream>>>(x, Wif, Wii, Wic, Wio, Z);

    lstm_persistent<<<dim3(NB), dim3(512), 0, stream>>>(
        Whf_w, Whi_w, Whc_w, Who_w, Whf_b, Whi_b, Whc_b, Who_b, Z, Hall, bar);

    phaseC_kernel<<<dim3(TT * 4), dim3(256), 0, stream>>>(lin_w, lin_b, Hall, out);
}